// Round 1
// baseline (391.486 us; speedup 1.0000x reference)
//
#include <hip/hip_runtime.h>

#define D 64
#define N_USERS 100000
#define N_ITEMS 50000
#define RW 64                              // rows per bucket
#define B_UI ((N_ITEMS + RW - 1) / RW)     // 782 item buckets
#define B_IU ((N_USERS + RW - 1) / RW)     // 1563 user buckets
#define B_TOT (B_UI + B_IU)                // 2345
#define CHUNK 8192                         // edges per pass-1 block
#define TILE 2048                          // pass-2 edge tile (8 per thread)
#define SCAN_TILE 1024

static inline size_t align16(size_t x) { return (x + 15) & ~(size_t)15; }

// fp32 -> bf16 (RNE), packed two per uint (elem 2k low, 2k+1 high)
__device__ inline unsigned int bf16rne(float f) {
    unsigned int b = __float_as_uint(f);
    return (b + 0x7fffu + ((b >> 16) & 1u)) >> 16;
}
__device__ inline float bf16lo(unsigned int u) { return __uint_as_float(u << 16); }
__device__ inline float bf16hi(unsigned int u) { return __uint_as_float(u & 0xffff0000u); }

// ---------------- feature conversion fp32 -> bf16 (proven round 5) ----------------
__global__ void convert_feats_kernel(const float* __restrict__ user_feat,
                                     const float* __restrict__ item_feat,
                                     unsigned int* __restrict__ user16,
                                     unsigned int* __restrict__ item16) {
    const long long USER_ELEMS = (long long)N_USERS * D;
    const long long TOTAL = USER_ELEMS + (long long)N_ITEMS * D;
    long long i4 = ((long long)blockIdx.x * blockDim.x + threadIdx.x) * 4;
    const long long stride = (long long)gridDim.x * blockDim.x * 4;
    for (; i4 < TOTAL; i4 += stride) {
        const float4 v = (i4 < USER_ELEMS)
            ? *(const float4*)(user_feat + i4)
            : *(const float4*)(item_feat + (i4 - USER_ELEMS));
        uint2 p;
        p.x = bf16rne(v.x) | (bf16rne(v.y) << 16);
        p.y = bf16rne(v.z) | (bf16rne(v.w) << 16);
        unsigned int* dst = (i4 < USER_ELEMS) ? (user16 + (i4 >> 1))
                                              : (item16 + ((i4 - USER_ELEMS) >> 1));
        *(uint2*)dst = p;
    }
}

// ---------------- pass 1a: per-chunk LDS histogram over dst buckets ----------------
__global__ void p1_count_kernel(const int* __restrict__ ui_dst,
                                const int* __restrict__ iu_dst,
                                int* __restrict__ counts,
                                int n_ui, int n_iu, int NB_ui, int NB) {
    __shared__ int hist[B_TOT];
    const int blk = blockIdx.x;
    for (int b = threadIdx.x; b < B_TOT; b += blockDim.x) hist[b] = 0;
    __syncthreads();
    const bool is_ui = blk < NB_ui;
    const int* dst = is_ui ? ui_dst : iu_dst;
    const int n = is_ui ? n_ui : n_iu;
    const int boff = is_ui ? 0 : B_UI;
    const int e0 = (is_ui ? blk : blk - NB_ui) * CHUNK;
    for (int k = 0; k < CHUNK; k += blockDim.x) {
        const int t = e0 + k + threadIdx.x;
        if (t < n) atomicAdd(&hist[boff + (dst[t] >> 6)], 1);
    }
    __syncthreads();
    for (int b = threadIdx.x; b < B_TOT; b += blockDim.x)
        counts[(long long)b * NB + blk] = hist[b];
}

// ---------------- scan machinery (round-2 proven scanA + wide single-block) -------
__global__ void scanA_kernel(int* __restrict__ data, int* __restrict__ tile_sums, int n) {
    __shared__ int lds[256];
    const int t = threadIdx.x;
    const int base = blockIdx.x * SCAN_TILE + t * 4;
    int v[4];
#pragma unroll
    for (int k = 0; k < 4; k++) v[k] = (base + k < n) ? data[base + k] : 0;
    const int s = v[0] + v[1] + v[2] + v[3];
    lds[t] = s;
    __syncthreads();
    for (int off = 1; off < 256; off <<= 1) {
        int x = (t >= off) ? lds[t - off] : 0;
        __syncthreads();
        lds[t] += x;
        __syncthreads();
    }
    const int incl = lds[t];
    const int excl = incl - s;
    if (t == 255) tile_sums[blockIdx.x] = incl;
    int run = excl;
#pragma unroll
    for (int k = 0; k < 4; k++) {
        int val = v[k];
        if (base + k < n) data[base + k] = run;
        run += val;
    }
}

// single block, 1024 threads, exclusive-scans up to 2048 tile sums
__global__ void scanB_big_kernel(int* __restrict__ tile_sums, int ntiles) {
    __shared__ int lds[1024];
    const int t = threadIdx.x;
    const int a = (2 * t < ntiles) ? tile_sums[2 * t] : 0;
    const int b = (2 * t + 1 < ntiles) ? tile_sums[2 * t + 1] : 0;
    const int s = a + b;
    lds[t] = s;
    __syncthreads();
    for (int off = 1; off < 1024; off <<= 1) {
        int x = (t >= off) ? lds[t - off] : 0;
        __syncthreads();
        lds[t] += x;
        __syncthreads();
    }
    const int excl = lds[t] - s;
    if (2 * t < ntiles) tile_sums[2 * t] = excl;
    if (2 * t + 1 < ntiles) tile_sums[2 * t + 1] = excl + a;
}

__global__ void scanC_kernel(int* __restrict__ data, const int* __restrict__ tile_sums, int n) {
    const int base = blockIdx.x * SCAN_TILE + threadIdx.x * 4;
    const int add = tile_sums[blockIdx.x];
#pragma unroll
    for (int k = 0; k < 4; k++) {
        const int i = base + k;
        if (i < n) data[i] += add;
    }
}

// ---------------- pass 1b: scatter edges bucket-grouped (LDS cursors) -------------
__global__ void p1_scatter_kernel(const int* __restrict__ ui_src,
                                  const int* __restrict__ iu_src,
                                  const int* __restrict__ ui_dst,
                                  const int* __restrict__ iu_dst,
                                  const float* __restrict__ norm_ui,
                                  const float* __restrict__ norm_iu,
                                  const int* __restrict__ counts,
                                  int2* __restrict__ part,
                                  int n_ui, int n_iu, int NB_ui, int NB) {
    __shared__ int cur[B_TOT];
    const int blk = blockIdx.x;
    for (int b = threadIdx.x; b < B_TOT; b += blockDim.x)
        cur[b] = counts[(long long)b * NB + blk];
    __syncthreads();
    const bool is_ui = blk < NB_ui;
    const int* src = is_ui ? ui_src : iu_src;
    const int* dst = is_ui ? ui_dst : iu_dst;
    const float* nrm = is_ui ? norm_ui : norm_iu;
    const int n = is_ui ? n_ui : n_iu;
    const int boff = is_ui ? 0 : B_UI;
    const int e0 = (is_ui ? blk : blk - NB_ui) * CHUNK;
    for (int k = 0; k < CHUNK; k += blockDim.x) {
        const int t = e0 + k + threadIdx.x;
        if (t < n) {
            const int d = dst[t];
            const int b = boff + (d >> 6);
            const int pos = atomicAdd(&cur[b], 1);
            part[pos] = make_int2(src[t] | ((d & 63) << 26), __float_as_int(nrm[t]));
        }
    }
}

// ---------------- pass 2: fused LDS counting-sort + gather --------------------
// Block = bucket (64 output rows). Tiles of 2048 edges: LDS sort by row, then
// waves accumulate rows with 8 independent bf16 feature loads in flight.
__global__ __launch_bounds__(256) void p2_gather_kernel(
        const uint4* __restrict__ user16, const uint4* __restrict__ item16,
        const int2* __restrict__ part, const int* __restrict__ counts,
        float* __restrict__ h_user, float* __restrict__ h_item,
        int NB, int n_total) {
    __shared__ int2 sorted[TILE];        // 16 KB
    __shared__ float acc[RW * D];        // 16 KB
    __shared__ int cnt[RW], offs[RW], cursor[RW], cnt2[RW];
    const int b = blockIdx.x;
    const int tid = threadIdx.x;
    const int lane = tid & 63;
    const int wave = tid >> 6;

    const int E0 = counts[(long long)b * NB];
    const int E1 = (b + 1 < B_TOT) ? counts[(long long)(b + 1) * NB] : n_total;

    const bool item_side = b < B_UI;
    const uint4* __restrict__ feat = item_side ? user16 : item16;
    const int baseRow = (item_side ? b : b - B_UI) * RW;

    for (int i = tid; i < RW * D; i += 256) acc[i] = 0.f;

    for (int base = E0; base < E1; base += TILE) {
        const int tileN = min(TILE, E1 - base);
        if (tid < RW) cnt[tid] = 0;
        __syncthreads();                           // A: acc/sorted free, cnt zeroed
        int2 v[TILE / 256];
#pragma unroll
        for (int k = 0; k < TILE / 256; k++) {
            const int t = tid + k * 256;
            if (t < tileN) {
                v[k] = part[base + t];
                atomicAdd(&cnt[((unsigned)v[k].x) >> 26], 1);
            }
        }
        __syncthreads();                           // B
        if (tid < RW) {  // wave 0 scans 64 counts
            const int c = cnt[tid];
            int incl = c;
            for (int dd = 1; dd < RW; dd <<= 1) {
                const int u = __shfl_up(incl, dd, 64);
                if (lane >= dd) incl += u;
            }
            offs[tid] = incl - c;
            cursor[tid] = incl - c;
            cnt2[tid] = c;
        }
        __syncthreads();                           // C
#pragma unroll
        for (int k = 0; k < TILE / 256; k++) {
            const int t = tid + k * 256;
            if (t < tileN) {
                const int r6 = ((unsigned)v[k].x) >> 26;
                const int pos = atomicAdd(&cursor[r6], 1);
                sorted[pos] = v[k];
            }
        }
        __syncthreads();                           // D
        for (int r = wave; r < RW; r += 4) {
            const int s = offs[r], c = cnt2[r];
            if (c == 0) continue;
            const int sub = lane & 7;
            float a0 = 0, a1 = 0, a2 = 0, a3 = 0, a4 = 0, a5 = 0, a6 = 0, a7 = 0;
            for (int j = lane >> 3; j < c; j += 8) {
                const int2 ed = sorted[s + j];
                const int srcRow = ed.x & 0x03FFFFFF;
                const float nv = __int_as_float(ed.y);
                const uint4 f = feat[srcRow * 8 + sub];
                a0 = fmaf(nv, bf16lo(f.x), a0);
                a1 = fmaf(nv, bf16hi(f.x), a1);
                a2 = fmaf(nv, bf16lo(f.y), a2);
                a3 = fmaf(nv, bf16hi(f.y), a3);
                a4 = fmaf(nv, bf16lo(f.z), a4);
                a5 = fmaf(nv, bf16hi(f.z), a5);
                a6 = fmaf(nv, bf16lo(f.w), a6);
                a7 = fmaf(nv, bf16hi(f.w), a7);
            }
            // reduce across the 8 edge-groups (lane bits 3..5)
            for (int m = 8; m <= 32; m <<= 1) {
                a0 += __shfl_xor(a0, m, 64);
                a1 += __shfl_xor(a1, m, 64);
                a2 += __shfl_xor(a2, m, 64);
                a3 += __shfl_xor(a3, m, 64);
                a4 += __shfl_xor(a4, m, 64);
                a5 += __shfl_xor(a5, m, 64);
                a6 += __shfl_xor(a6, m, 64);
                a7 += __shfl_xor(a7, m, 64);
            }
            if (lane < 8) {
                float4* ap = (float4*)&acc[r * D + lane * 8];
                float4 q0 = ap[0], q1 = ap[1];
                q0.x += a0; q0.y += a1; q0.z += a2; q0.w += a3;
                q1.x += a4; q1.y += a5; q1.z += a6; q1.w += a7;
                ap[0] = q0; ap[1] = q1;
            }
        }
    }
    __syncthreads();
    // write out 64 rows x 64 floats, coalesced float4
    float* __restrict__ outp = item_side ? h_item : h_user;
    const int limit = item_side ? N_ITEMS : N_USERS;
#pragma unroll
    for (int it = 0; it < 4; it++) {
        const int i4 = tid + it * 256;          // float4 index in [0,1024)
        const int r = (i4 * 4) >> 6;
        const int row = baseRow + r;
        if (row < limit) {
            *(float4*)&outp[(long long)row * D + ((i4 * 4) & 63)] = *(float4*)&acc[i4 * 4];
        }
    }
}

// ---------------- fallback: atomic scatter (round-1 proven) ----------------
__global__ void scatter_rel_kernel(const float* __restrict__ feat,
                                   const float* __restrict__ norm,
                                   const int* __restrict__ src,
                                   const int* __restrict__ dst,
                                   float* __restrict__ out, int n_edges) {
    const int lane = threadIdx.x & 63;
    const int wib = threadIdx.x >> 6;
    const int wpb = blockDim.x >> 6;
    long long e = (long long)blockIdx.x * wpb + wib;
    const long long stride = (long long)gridDim.x * wpb;
    for (; e < n_edges; e += stride) {
        atomicAdd(&out[(long long)dst[e] * D + lane],
                  norm[e] * feat[(long long)src[e] * D + lane]);
    }
}

extern "C" void kernel_launch(void* const* d_in, const int* in_sizes, int n_in,
                              void* d_out, int out_size, void* d_ws, size_t ws_size,
                              hipStream_t stream) {
    const float* user_feat = (const float*)d_in[0];
    const float* item_feat = (const float*)d_in[1];
    const float* norm_ui   = (const float*)d_in[2];
    const float* norm_iu   = (const float*)d_in[3];
    const int*   ui_src    = (const int*)d_in[4];  // user idx
    const int*   ui_dst    = (const int*)d_in[5];  // item idx
    const int*   iu_src    = (const int*)d_in[6];  // item idx
    const int*   iu_dst    = (const int*)d_in[7];  // user idx

    const int n_ui = in_sizes[4];
    const int n_iu = in_sizes[6];
    const int n_total = n_ui + n_iu;

    float* h_user = (float*)d_out;                              // [N_USERS, D]
    float* h_item = (float*)d_out + (long long)N_USERS * D;     // [N_ITEMS, D]

    const int block = 256;
    const int NB_ui = (n_ui + CHUNK - 1) / CHUNK;
    const int NB_iu = (n_iu + CHUNK - 1) / CHUNK;
    const int NB = NB_ui + NB_iu;
    const int scan_n = B_TOT * NB;
    const int ntiles = (scan_n + SCAN_TILE - 1) / SCAN_TILE;

    // ---- workspace layout ----
    char* ws = (char*)d_ws;
    size_t off = 0;
    int* counts = (int*)(ws + off);  off += align16((size_t)scan_n * 4);
    int* tsums  = (int*)(ws + off);  off += align16((size_t)2048 * 4);
    int2* part  = (int2*)(ws + off); off += align16((size_t)n_total * 8);
    unsigned int* user16 = (unsigned int*)(ws + off); off += align16((size_t)N_USERS * D * 2);
    unsigned int* item16 = (unsigned int*)(ws + off); off += align16((size_t)N_ITEMS * D * 2);
    const size_t needed = off;

    if (ws_size < needed || ntiles > 2048) {
        // fallback: atomic-scatter path
        hipMemsetAsync(d_out, 0, (size_t)out_size * sizeof(float), stream);
        const int wpb = block / 64;
        scatter_rel_kernel<<<(n_ui + wpb - 1) / wpb, block, 0, stream>>>(
            user_feat, norm_ui, ui_src, ui_dst, h_item, n_ui);
        scatter_rel_kernel<<<(n_iu + wpb - 1) / wpb, block, 0, stream>>>(
            item_feat, norm_iu, iu_src, iu_dst, h_user, n_iu);
        return;
    }

    // 0. fp32 -> bf16 feature tables
    const long long cv_threads = ((long long)(N_USERS + N_ITEMS) * D) / 4;
    convert_feats_kernel<<<(int)((cv_threads + block - 1) / block), block, 0, stream>>>(
        user_feat, item_feat, user16, item16);

    // 1. per-chunk bucket histograms (LDS atomics only)
    p1_count_kernel<<<NB, block, 0, stream>>>(ui_dst, iu_dst, counts,
                                              n_ui, n_iu, NB_ui, NB);

    // 2. exclusive scan of counts (bucket-major)
    scanA_kernel<<<ntiles, 256, 0, stream>>>(counts, tsums, scan_n);
    scanB_big_kernel<<<1, 1024, 0, stream>>>(tsums, ntiles);
    scanC_kernel<<<ntiles, 256, 0, stream>>>(counts, tsums, scan_n);

    // 3. scatter edges into bucket-grouped order
    p1_scatter_kernel<<<NB, block, 0, stream>>>(ui_src, iu_src, ui_dst, iu_dst,
                                                norm_ui, norm_iu, counts, part,
                                                n_ui, n_iu, NB_ui, NB);

    // 4. fused sort+gather, one block per bucket (writes every output row)
    p2_gather_kernel<<<B_TOT, block, 0, stream>>>(
        (const uint4*)user16, (const uint4*)item16, part, counts,
        h_user, h_item, NB, n_total);
}